// Round 4
// baseline (647.816 us; speedup 1.0000x reference)
//
#include <hip/hip_runtime.h>

#define S_TOK 8192
#define H_DIM 1024
#define NE    8
#define CAP   1024
#define DFF   4096

typedef unsigned short u16;
typedef __bf16 bf16_t;
typedef bf16_t bf16x8 __attribute__((ext_vector_type(8)));
typedef float  f32x4  __attribute__((ext_vector_type(4)));

// B LDS layout: [128 rows][stride 40 bf16] -> 80 B row pitch (16B-aligned),
// bank stride 20 words (8 distinct banks) -> b128 frag reads ~2-way (free),
// b64 staged writes ~8-way (acceptable).
#define BSTRIDE 40

__device__ __forceinline__ u16 f2bf(float f) {
  union { float f; unsigned u; } a; a.f = f;
  unsigned u = a.u;
  u += 0x7fffu + ((u >> 16) & 1u);   // RNE
  return (u16)(u >> 16);
}

__device__ __forceinline__ float gelu_tanh(float x) {
  const float c = 0.7978845608028654f;
  float t = tanhf(c * (x + 0.044715f * x * x * x));
  return 0.5f * x * (1.0f + t);
}

// ---------------- gating: logits, softmax, argmax, per-block rank/histogram ----------
__global__ void gate_kernel(const float* __restrict__ x, const float* __restrict__ wg,
                            float* __restrict__ gate, int* __restrict__ expert,
                            int* __restrict__ rank, int* __restrict__ blockCnt,
                            float* __restrict__ blockMe) {
  __shared__ float sg[16][8];
  __shared__ int   se[16];
  int tid = threadIdx.x, lane = tid & 63, w = tid >> 6;
  int b = blockIdx.x;
  for (int j = 0; j < 4; ++j) {
    int t = w * 4 + j;
    int s = b * 16 + t;
    const float* xr = x + (size_t)s * H_DIM;
    float acc[8];
#pragma unroll
    for (int e = 0; e < 8; ++e) acc[e] = 0.f;
#pragma unroll
    for (int i = 0; i < 16; ++i) {
      int h = i * 64 + lane;
      float xv = xr[h];
      float4 wa = *(const float4*)(wg + h * 8);
      float4 wb = *(const float4*)(wg + h * 8 + 4);
      acc[0] += xv * wa.x; acc[1] += xv * wa.y; acc[2] += xv * wa.z; acc[3] += xv * wa.w;
      acc[4] += xv * wb.x; acc[5] += xv * wb.y; acc[6] += xv * wb.z; acc[7] += xv * wb.w;
    }
#pragma unroll
    for (int off = 32; off >= 1; off >>= 1)
#pragma unroll
      for (int e = 0; e < 8; ++e) acc[e] += __shfl_down(acc[e], off);
    if (lane == 0) {
      float mx = acc[0];
#pragma unroll
      for (int e = 1; e < 8; ++e) mx = fmaxf(mx, acc[e]);
      float g[8], Z = 0.f;
#pragma unroll
      for (int e = 0; e < 8; ++e) { g[e] = expf(acc[e] - mx); Z += g[e]; }
      int am = 0; float best = acc[0];
#pragma unroll
      for (int e = 1; e < 8; ++e) if (acc[e] > best) { best = acc[e]; am = e; }
      float inv = 1.f / Z;
#pragma unroll
      for (int e = 0; e < 8; ++e) sg[t][e] = g[e] * inv;
      se[t] = am;
      gate[s] = g[am] * inv;
      expert[s] = am;
    }
  }
  __syncthreads();
  if (tid < 16) {
    int e = se[tid], r = 0;
    for (int t2 = 0; t2 < tid; ++t2) r += (se[t2] == e) ? 1 : 0;
    rank[b * 16 + tid] = r;
  }
  if (tid < 8) {
    int c = 0; float m = 0.f;
#pragma unroll
    for (int t = 0; t < 16; ++t) { c += (se[t] == tid) ? 1 : 0; m += sg[t][tid]; }
    blockCnt[b * 8 + tid] = c;
    blockMe[b * 8 + tid] = m;
  }
}

// ------------- scan over 512 block histograms; l_aux + exp_counts to out tail --------
__global__ void scan_kernel(const int* __restrict__ blockCnt, const float* __restrict__ blockMe,
                            int* __restrict__ blockOff, int* __restrict__ counts,
                            float* __restrict__ tail) {
  int tid = threadIdx.x;
  int e = tid >> 6, lane = tid & 63;   // one wave per expert
  int run = 0; float msum = 0.f;
  for (int c = 0; c < 8; ++c) {
    int b = c * 64 + lane;
    int v = blockCnt[b * 8 + e];
    float mv = blockMe[b * 8 + e];
    int sc = v;
#pragma unroll
    for (int off = 1; off < 64; off <<= 1) {
      int u = __shfl_up(sc, off);
      if (lane >= off) sc += u;
    }
    blockOff[b * 8 + e] = run + sc - v;
    run += __shfl(sc, 63);
#pragma unroll
    for (int off = 32; off >= 1; off >>= 1) mv += __shfl_down(mv, off);
    msum += __shfl(mv, 0);
  }
  __shared__ float sm[8];
  __shared__ int scnt[8];
  if (lane == 0) {
    sm[e] = msum; scnt[e] = run;
    counts[e] = run < CAP ? run : CAP;
  }
  __syncthreads();
  if (tid == 0) {
    float la = 0.f;
    for (int i = 0; i < 8; ++i)
      la += (sm[i] / (float)S_TOK) * ((float)scnt[i] / (float)S_TOK);
    tail[0] = la * (float)NE;
    for (int i = 0; i < 8; ++i) {
      int cc = scnt[i] < CAP ? scnt[i] : CAP;
      tail[1 + i] = (float)cc;
    }
  }
}

// ---------------- slot assignment ----------------------------------------------------
__global__ void assign_kernel(const int* __restrict__ expert, const int* __restrict__ rank,
                              const int* __restrict__ blockOff, int* __restrict__ slot_token) {
  int s = blockIdx.x * 256 + threadIdx.x;
  int e = expert[s];
  int pos = blockOff[(s >> 4) * 8 + e] + rank[s];
  if (pos < CAP) slot_token[e * CAP + pos] = s;
}

// ---------------- gather tokens into expert slots (fp32 -> bf16) ---------------------
__global__ void gather_kernel(const float* __restrict__ x, const int* __restrict__ slot_token,
                              const int* __restrict__ counts, u16* __restrict__ disp) {
  int slot = blockIdx.x;
  int e = slot >> 10, c = slot & 1023;
  int t = threadIdx.x;
  ushort4 v4;
  if (c < counts[e]) {
    int s = slot_token[slot];
    float4 v = *(const float4*)(x + (size_t)s * H_DIM + t * 4);
    v4.x = f2bf(v.x); v4.y = f2bf(v.y); v4.z = f2bf(v.z); v4.w = f2bf(v.w);
  } else {
    v4.x = 0; v4.y = 0; v4.z = 0; v4.w = 0;
  }
  *(ushort4*)(disp + (size_t)slot * H_DIM + t * 4) = v4;
}

// ---------------- fused GEMM core: A bf16 (glds), B fp32 transposed-in-LDS -----------
// Block 128x128, 4 waves, BK=32. A LDS: 8KB XOR-swizzled. B LDS: [128][BSTRIDE].
// B staging: thread t handles col n=t&127, k-half kh=t>>7; per iter 16 dword loads
// (lane==n -> coalesced 256B rows) + 4 ds_write_b64 of packed bf16 k-quads.
template <int NITER>
__device__ __forceinline__ void gemm_fused(const u16* __restrict__ A, int lda,
                                           const float* __restrict__ Bsrc, int ldn,
                                           u16* As, u16* Bs, f32x4 acc[4][4]) {
  int tid = threadIdx.x;
  int lane = tid & 63;
  int w = tid >> 6, wm = w >> 1, wn = w & 1;
  int q = lane >> 4, l15 = lane & 15;

  // A staging: 2 chunks/thread, XOR swizzle ((row>>1)&3)
  const u16* agp[2]; u16* alp[2];
#pragma unroll
  for (int r = 0; r < 2; ++r) {
    int p = (w * 2 + r) * 64 + lane;
    int row = p >> 2;
    int kq = (p & 3) ^ ((row >> 1) & 3);
    agp[r] = A + (size_t)row * lda + kq * 8;
    alp[r] = As + (w * 2 + r) * 512;
  }

  // B staging: col nb, k rows kh*16 .. kh*16+15
  int nb = tid & 127, kh = tid >> 7;
  const float* bbase = Bsrc + (size_t)(kh * 16) * ldn + nb;
  u16* bdst = Bs + nb * BSTRIDE + kh * 16;

  // fragment offsets
  int aoff[4], boff[4];
#pragma unroll
  for (int t = 0; t < 4; ++t) {
    int ra = wm * 64 + t * 16 + l15;
    aoff[t] = ra * 32 + ((q ^ ((ra >> 1) & 3)) * 8);
    int rb = wn * 64 + t * 16 + l15;
    boff[t] = rb * BSTRIDE + q * 8;
  }

  for (int kit = 0; kit < NITER; ++kit) {
    int kt = kit * 32;
#pragma unroll
    for (int r = 0; r < 2; ++r)
      __builtin_amdgcn_global_load_lds((__attribute__((address_space(1))) int*)(agp[r] + kt),
                                       (__attribute__((address_space(3))) int*)(alp[r]),
                                       16, 0, 0);
    float v[16];
    const float* bp = bbase + (size_t)kt * ldn;
#pragma unroll
    for (int i = 0; i < 16; ++i) v[i] = bp[(size_t)i * ldn];
#pragma unroll
    for (int p = 0; p < 4; ++p) {
      unsigned lo = (unsigned)f2bf(v[p * 4 + 0]) | ((unsigned)f2bf(v[p * 4 + 1]) << 16);
      unsigned hi = (unsigned)f2bf(v[p * 4 + 2]) | ((unsigned)f2bf(v[p * 4 + 3]) << 16);
      uint2 pk; pk.x = lo; pk.y = hi;
      *(uint2*)(bdst + p * 4) = pk;
    }
    __syncthreads();
    bf16x8 af[4], bfr[4];
#pragma unroll
    for (int t = 0; t < 4; ++t) af[t] = *(const bf16x8*)(As + aoff[t]);
#pragma unroll
    for (int t = 0; t < 4; ++t) bfr[t] = *(const bf16x8*)(Bs + boff[t]);
#pragma unroll
    for (int mt = 0; mt < 4; ++mt)
#pragma unroll
      for (int nt = 0; nt < 4; ++nt)
        acc[mt][nt] = __builtin_amdgcn_mfma_f32_16x16x32_bf16(af[mt], bfr[nt], acc[mt][nt], 0, 0, 0);
    __syncthreads();
  }
}

// ---------------- GEMM1: h1 = gelu(disp @ w1 + b1), bf16 out -------------------------
__global__ __launch_bounds__(256, 2) void gemm1_kernel(const u16* __restrict__ disp,
                                                       const float* __restrict__ w1,
                                                       const float* __restrict__ b1,
                                                       u16* __restrict__ h1) {
  __shared__ __align__(16) u16 As[4096];
  __shared__ __align__(16) u16 Bs[128 * BSTRIDE];
  int e = blockIdx.z;
  int m0 = blockIdx.y * 128, n0 = blockIdx.x * 128;
  const u16* A = disp + (size_t)e * CAP * H_DIM + (size_t)m0 * H_DIM;
  const float* Bsrc = w1 + (size_t)e * H_DIM * DFF + n0;   // [k][n] rows, n0 col offset
  f32x4 acc[4][4];
  f32x4 zero = {0.f, 0.f, 0.f, 0.f};
#pragma unroll
  for (int i = 0; i < 4; ++i)
#pragma unroll
    for (int j = 0; j < 4; ++j) acc[i][j] = zero;
  gemm_fused<H_DIM / 32>(A, H_DIM, Bsrc, DFF, As, Bs, acc);
  int tid = threadIdx.x, lane = tid & 63, w = tid >> 6, wm = w >> 1, wn = w & 1;
  int q = lane >> 4, l15 = lane & 15;
  const float* b1e = b1 + e * DFF;
  u16* out = h1 + (size_t)e * CAP * DFF;
#pragma unroll
  for (int mt = 0; mt < 4; ++mt)
#pragma unroll
    for (int nt = 0; nt < 4; ++nt) {
      int col = n0 + wn * 64 + nt * 16 + l15;
      float bias = b1e[col];
#pragma unroll
      for (int r = 0; r < 4; ++r) {
        int row = m0 + wm * 64 + mt * 16 + q * 4 + r;
        out[(size_t)row * DFF + col] = f2bf(gelu_tanh(acc[mt][nt][r] + bias));
      }
    }
}

// ---------------- GEMM2: K-split x2, raw fp32 partials to ws -------------------------
// grid (8 n, 8 m, 16 = e*2+slice); each block does K in [slice*2048, slice*2048+2048)
__global__ __launch_bounds__(256, 2) void gemm2_kernel(const u16* __restrict__ h1,
                                                       const float* __restrict__ w2,
                                                       float* __restrict__ part) {
  __shared__ __align__(16) u16 As[4096];
  __shared__ __align__(16) u16 Bs[128 * BSTRIDE];
  int ez = blockIdx.z;
  int e = ez >> 1, slice = ez & 1;
  int m0 = blockIdx.y * 128, n0 = blockIdx.x * 128;
  const u16* A = h1 + (size_t)e * CAP * DFF + (size_t)m0 * DFF + slice * 2048;
  const float* Bsrc = w2 + (size_t)e * DFF * H_DIM + (size_t)(slice * 2048) * H_DIM + n0;
  f32x4 acc[4][4];
  f32x4 zero = {0.f, 0.f, 0.f, 0.f};
#pragma unroll
  for (int i = 0; i < 4; ++i)
#pragma unroll
    for (int j = 0; j < 4; ++j) acc[i][j] = zero;
  gemm_fused<2048 / 32>(A, DFF, Bsrc, H_DIM, As, Bs, acc);
  int tid = threadIdx.x, lane = tid & 63, w = tid >> 6, wm = w >> 1, wn = w & 1;
  int q = lane >> 4, l15 = lane & 15;
  float* pout = part + ((size_t)(slice * 8 + e) * CAP) * H_DIM;
#pragma unroll
  for (int mt = 0; mt < 4; ++mt)
#pragma unroll
    for (int nt = 0; nt < 4; ++nt) {
      int col = n0 + wn * 64 + nt * 16 + l15;
#pragma unroll
      for (int r = 0; r < 4; ++r) {
        int row = m0 + wm * 64 + mt * 16 + q * 4 + r;
        pout[(size_t)row * H_DIM + col] = acc[mt][nt][r];
      }
    }
}

// ---------------- combine: out[token] = gate * (p0 + p1 + b2) ------------------------
__global__ void combine_kernel(const float* __restrict__ part, const float* __restrict__ b2,
                               const int* __restrict__ slot_token,
                               const float* __restrict__ gate,
                               const int* __restrict__ counts, float* __restrict__ out) {
  int slot = blockIdx.x;
  int e = slot >> 10, c = slot & 1023;
  if (c >= counts[e]) return;
  int s = slot_token[slot];
  float g = gate[s];
  int t = threadIdx.x;
  size_t base0 = ((size_t)e * CAP + c) * H_DIM + t * 4;
  size_t base1 = ((size_t)(8 + e) * CAP + c) * H_DIM + t * 4;
  float4 p0 = *(const float4*)(part + base0);
  float4 p1 = *(const float4*)(part + base1);
  float4 bb = *(const float4*)(b2 + e * H_DIM + t * 4);
  float4 o;
  o.x = g * (p0.x + p1.x + bb.x);
  o.y = g * (p0.y + p1.y + bb.y);
  o.z = g * (p0.z + p1.z + bb.z);
  o.w = g * (p0.w + p1.w + bb.w);
  *(float4*)(out + (size_t)s * H_DIM + t * 4) = o;
}

extern "C" void kernel_launch(void* const* d_in, const int* in_sizes, int n_in,
                              void* d_out, int out_size, void* d_ws, size_t ws_size,
                              hipStream_t stream) {
  const float* x  = (const float*)d_in[0];
  const float* wg = (const float*)d_in[1];
  const float* w1 = (const float*)d_in[2];
  const float* b1 = (const float*)d_in[3];
  const float* w2 = (const float*)d_in[4];
  const float* b2 = (const float*)d_in[5];
  float* out = (float*)d_out;
  char* ws = (char*)d_ws;
  const size_t MB = 1024 * 1024;
  // ws layout: part 64MB | disp 16MB | h1 64MB | small buffers (~200KB)
  float* part = (float*)(ws);
  u16* disp = (u16*)(ws + 64 * MB);
  u16* h1   = (u16*)(ws + 80 * MB);
  char* sm = ws + 144 * MB;
  float* gate      = (float*)(sm);
  int*   expert    = (int*)(sm + 32 * 1024);
  int*   rank      = (int*)(sm + 64 * 1024);
  int*   slot_tok  = (int*)(sm + 96 * 1024);
  int*   blockCnt  = (int*)(sm + 128 * 1024);
  int*   blockOff  = (int*)(sm + 144 * 1024);
  float* blockMe   = (float*)(sm + 160 * 1024);
  int*   counts    = (int*)(sm + 176 * 1024);

  hipMemsetAsync(d_out, 0, (size_t)out_size * sizeof(float), stream);
  gate_kernel<<<512, 256, 0, stream>>>(x, wg, gate, expert, rank, blockCnt, blockMe);
  scan_kernel<<<1, 512, 0, stream>>>(blockCnt, blockMe, blockOff, counts,
                                     out + (size_t)S_TOK * H_DIM);
  assign_kernel<<<32, 256, 0, stream>>>(expert, rank, blockOff, slot_tok);
  gather_kernel<<<8192, 256, 0, stream>>>(x, slot_tok, counts, disp);
  gemm1_kernel<<<dim3(DFF / 128, CAP / 128, NE), 256, 0, stream>>>(disp, w1, b1, h1);
  gemm2_kernel<<<dim3(H_DIM / 128, CAP / 128, NE * 2), 256, 0, stream>>>(h1, w2, part);
  combine_kernel<<<NE * CAP, 256, 0, stream>>>(part, b2, slot_tok, gate, counts, out);
}